// Round 1
// baseline (1425.374 us; speedup 1.0000x reference)
//
#include <hip/hip_runtime.h>
#include <hip/hip_bf16.h>
#include <math.h>

// ---- types ----------------------------------------------------------------
typedef __attribute__((ext_vector_type(8))) __bf16 bf16x8;
typedef __attribute__((ext_vector_type(8))) short  s16x8;
typedef __attribute__((ext_vector_type(4))) float  f32x4;
union SB8 { s16x8 s; bf16x8 b; };

__device__ __forceinline__ unsigned short f2bf(float f) {
  unsigned int u = __builtin_bit_cast(unsigned int, f);
  u = u + 0x7FFFu + ((u >> 16) & 1u);           // round-to-nearest-even
  return (unsigned short)(u >> 16);
}

// async global->LDS, 16B per lane; LDS dest = wave-uniform base + lane*16
__device__ __forceinline__ void glds16(const void* g, void* l) {
  __builtin_amdgcn_global_load_lds((const __attribute__((address_space(1))) void*)g,
                                   (__attribute__((address_space(3))) void*)l, 16, 0, 0);
}

#define B_  256
#define S_  300
#define D_  512
#define SP  320          // keys padded to 320 (zero pad)
#define M_  76800        // B_*S_

// ---- K0: x fp32 -> bf16 (vectorized, 8 elems/iter) ------------------------
__global__ __launch_bounds__(256) void k_cvt_x(const float* __restrict__ x,
                                               unsigned short* __restrict__ xb, int n8) {
  int i = blockIdx.x * blockDim.x + threadIdx.x;
  int stride = gridDim.x * blockDim.x;
  for (; i < n8; i += stride) {
    const float4* p = (const float4*)(x + (size_t)i * 8);
    float4 a = p[0], b = p[1];
    union { unsigned short u[8]; s16x8 v; } o;
    o.u[0]=f2bf(a.x); o.u[1]=f2bf(a.y); o.u[2]=f2bf(a.z); o.u[3]=f2bf(a.w);
    o.u[4]=f2bf(b.x); o.u[5]=f2bf(b.y); o.u[6]=f2bf(b.z); o.u[7]=f2bf(b.w);
    *(s16x8*)(xb + (size_t)i * 8) = o.v;
  }
}

// ---- K0b: W[3][512][512] -> Wt[3][512][512] (n-major) bf16 ----------------
__global__ __launch_bounds__(256) void k_wt(const float* __restrict__ w,
                                            unsigned short* __restrict__ wt) {
  int i = blockIdx.x * 256 + threadIdx.x;       // exactly 3*512*512 threads
  int p = i >> 18;
  int r = i & 262143;
  int k = r >> 9, n = r & 511;
  wt[p * 262144 + n * 512 + k] = f2bf(w[i]);
}

// ---- K1: QKV projection GEMM (m97 structure: 128x128, BK=32, 4 waves) -----
// A = x_bf16 [76800][512], B^T = Wt[p] [512][512], C -> bf16 Q/K/V
__global__ __launch_bounds__(256) void k_proj(const unsigned short* __restrict__ xb,
                                              const unsigned short* __restrict__ wt,
                                              unsigned short* __restrict__ qkv) {
  __shared__ short As[128 * 32];
  __shared__ short Bs[128 * 32];
  // XCD-bijective swizzle: 7200 = 8 * 900, 900 = 75 * 12; colocate the 12
  // (n0,p) blocks sharing one 128-row x-panel on one XCD.
  int bid = blockIdx.x;
  int xc = bid & 7, j = bid >> 3;
  int mt = xc + 8 * (j / 12);
  int tile = j % 12;
  int n0 = (tile & 3) * 128;
  int p  = tile >> 2;
  int rowBase = mt * 128;
  const unsigned short* wp = wt + p * 262144;
  unsigned short* outp = qkv + (size_t)p * ((size_t)M_ * 512);

  int tid = threadIdx.x, lane = tid & 63, wid = tid >> 6;
  int wr = wid >> 1, wc = wid & 1;
  int lr = lane >> 2, lk = (lane & 3) * 8;      // staging: row-in-chunk, k-off
  int kg = (lane >> 4) * 8, fr = lane & 15;     // fragment indices
  f32x4 acc[4][4] = {};

  for (int t = 0; t < 16; ++t) {
    int k0 = t * 32;
    for (int c = wid * 2; c < wid * 2 + 2; ++c)   // A: 8 chunks of 1KB
      glds16(xb + (size_t)(rowBase + c * 16 + lr) * 512 + k0 + lk,
             &As[c * 512 + lane * 8]);
    for (int c = wid * 2; c < wid * 2 + 2; ++c)   // B
      glds16(wp + (size_t)(n0 + c * 16 + lr) * 512 + k0 + lk,
             &Bs[c * 512 + lane * 8]);
    __syncthreads();
    SB8 aF[4], bF[4];
#pragma unroll
    for (int m = 0; m < 4; ++m)
      aF[m].s = *(const s16x8*)&As[(wr * 64 + m * 16 + fr) * 32 + kg];
#pragma unroll
    for (int n = 0; n < 4; ++n)
      bF[n].s = *(const s16x8*)&Bs[(wc * 64 + n * 16 + fr) * 32 + kg];
#pragma unroll
    for (int m = 0; m < 4; ++m)
#pragma unroll
      for (int n = 0; n < 4; ++n)
        acc[m][n] = __builtin_amdgcn_mfma_f32_16x16x32_bf16(aF[m].b, bF[n].b, acc[m][n], 0, 0, 0);
    __syncthreads();
  }
  int fq = lane >> 4;
#pragma unroll
  for (int m = 0; m < 4; ++m)
#pragma unroll
    for (int n = 0; n < 4; ++n) {
      int row = rowBase + wr * 64 + m * 16 + fq * 4;
      int col = n0 + wc * 64 + n * 16 + fr;
      unsigned short* o = outp + (size_t)row * 512 + col;
#pragma unroll
      for (int jj = 0; jj < 4; ++jj)
        o[(size_t)jj * 512] = f2bf(acc[m][n][jj]);
    }
}

// ---- K2: P = softmax(Q K^T / sqrt(300)) per (batch, 32-row q-tile) --------
// Q [32][512] LDS-resident, XOR-swizzled via pre-swizzled global source (T2/m173).
// K staged per 32-wide K-step. Waves split the 19 key-tiles (5/5/5/4).
__global__ __launch_bounds__(256) void k_attn_p(const unsigned short* __restrict__ Q,
                                                const unsigned short* __restrict__ K,
                                                unsigned short* __restrict__ P) {
  __shared__ union {
    struct { short q[32 * 512]; short k[304 * 32]; } s1;   // 52224 B
    float S[32 * 321];                                     // 41088 B
  } sm;
  int b = blockIdx.x, qt = blockIdx.y;
  int qBase = qt * 32;
  const unsigned short* Qb = Q + (size_t)b * S_ * 512;
  const unsigned short* Kb = K + (size_t)b * S_ * 512;
  unsigned short* Pb = P + (size_t)b * S_ * SP;
  int tid = threadIdx.x, lane = tid & 63, wid = tid >> 6;
  int lr = lane >> 2, lk = (lane & 3) * 8;
  int kg = (lane >> 4) * 8, fr = lane & 15;

  // stage Q once (32 chunks = 32 rows); source pre-swizzled so LDS holds
  // content[r][p] = Q[r][p ^ ((r&7)*8)]
  for (int c = wid * 8; c < wid * 8 + 8; ++c) {
    int qr = qBase + c; if (qr > 299) qr = 299;
    int ke = (lane * 8) ^ ((c & 7) * 8);
    glds16(Qb + (size_t)qr * 512 + ke, &sm.s1.q[c * 512 + lane * 8]);
  }
  int ntBase = (wid < 3) ? wid * 5 : 15;
  int ntCnt  = (wid < 3) ? 5 : 4;
  f32x4 acc[2][5] = {};

  for (int t = 0; t < 16; ++t) {
    int k0 = t * 32;
    for (int c = wid; c < 19; c += 4) {          // K tile [304][32]
      int kr = c * 16 + lr; if (kr > 299) kr = 299;
      glds16(Kb + (size_t)kr * 512 + k0 + lk, &sm.s1.k[c * 512 + lane * 8]);
    }
    __syncthreads();
    SB8 qF[2], kF[5];
#pragma unroll
    for (int m = 0; m < 2; ++m) {
      int r = m * 16 + fr;
      int ko = (k0 + kg) ^ ((r & 7) * 8);        // swizzled read
      qF[m].s = *(const s16x8*)&sm.s1.q[r * 512 + ko];
    }
    for (int n = 0; n < ntCnt; ++n)
      kF[n].s = *(const s16x8*)&sm.s1.k[((ntBase + n) * 16 + fr) * 32 + kg];
#pragma unroll
    for (int m = 0; m < 2; ++m)
      for (int n = 0; n < ntCnt; ++n)
        acc[m][n] = __builtin_amdgcn_mfma_f32_16x16x32_bf16(qF[m].b, kF[n].b, acc[m][n], 0, 0, 0);
    __syncthreads();
  }

  // spill scores to LDS (scaled)
  const float scale = 0.05773502691896258f;      // 1/sqrt(300)
  for (int m = 0; m < 2; ++m)
    for (int n = 0; n < ntCnt; ++n) {
      int col = (ntBase + n) * 16 + fr;
      int rb = m * 16 + (lane >> 4) * 4;
#pragma unroll
      for (int jj = 0; jj < 4; ++jj)
        sm.S[(rb + jj) * 321 + col] = acc[m][n][jj] * scale;
    }
  __syncthreads();

  // wave-parallel softmax: 8 threads per row
  int r = tid >> 3, jj = tid & 7;
  int c0 = jj * 38, c1 = c0 + 38; if (c1 > 300) c1 = 300;
  float mx = -1e30f;
  for (int c = c0; c < c1; ++c) mx = fmaxf(mx, sm.S[r * 321 + c]);
  mx = fmaxf(mx, __shfl_xor(mx, 1));
  mx = fmaxf(mx, __shfl_xor(mx, 2));
  mx = fmaxf(mx, __shfl_xor(mx, 4));
  float sum = 0.f;
  for (int c = c0; c < c1; ++c) {
    float e = __expf(sm.S[r * 321 + c] - mx);
    sm.S[r * 321 + c] = e; sum += e;
  }
  sum += __shfl_xor(sum, 1);
  sum += __shfl_xor(sum, 2);
  sum += __shfl_xor(sum, 4);
  float inv = 1.0f / sum;
  int qrow = qBase + r;
  if (qrow < 300) {
    int ce = (jj == 7) ? 320 : c0 + 38;          // j==7 also zero-fills pad
    for (int c = c0; c < ce; ++c) {
      float v = (c < 300) ? sm.S[r * 321 + c] * inv : 0.f;
      Pb[(size_t)qrow * SP + c] = f2bf(v);
    }
  }
}

// ---- K1b: V [B][300][512] -> Vt [B][512][320] bf16, zero-padded -----------
__global__ __launch_bounds__(256) void k_vt(const unsigned short* __restrict__ V,
                                            unsigned short* __restrict__ Vt) {
  __shared__ unsigned short tile[32][33];
  int kt = blockIdx.x, nt = blockIdx.y, b = blockIdx.z;
  const unsigned short* Vb = V + (size_t)b * S_ * 512;
  unsigned short* Vtb = Vt + (size_t)b * 512 * SP;
  int tc = threadIdx.x & 31, tr = threadIdx.x >> 5;   // tr 0..7
#pragma unroll
  for (int i = 0; i < 4; ++i) {
    int k = kt * 32 + tr + i * 8;
    int n = nt * 32 + tc;
    tile[tr + i * 8][tc] = (k < 300) ? Vb[(size_t)k * 512 + n] : (unsigned short)0;
  }
  __syncthreads();
#pragma unroll
  for (int i = 0; i < 4; ++i) {
    int n = nt * 32 + tr + i * 8;
    int k = kt * 32 + tc;
    Vtb[(size_t)n * SP + k] = tile[tc][tr + i * 8];
  }
}

// ---- K3: O = P @ V  (A = P [300][320], B^T = Vt [512][320], C fp32) -------
__global__ __launch_bounds__(256) void k_pv(const unsigned short* __restrict__ P,
                                            const unsigned short* __restrict__ Vt,
                                            float* __restrict__ O) {
  __shared__ short As[128 * 32];
  __shared__ short Bs[128 * 32];
  int bid = blockIdx.x;                       // 3072 = 8*384, 384 = 32*12
  int xc = bid & 7, j = bid >> 3;
  int b = xc + 8 * (j / 12);
  int tile = j % 12;
  int mt = tile >> 2, n0 = (tile & 3) * 128;
  int rowBase = mt * 128;
  const unsigned short* Pb  = P  + (size_t)b * S_ * SP;
  const unsigned short* Vtb = Vt + (size_t)b * 512 * SP;
  float* Ob = O + (size_t)b * S_ * 512;
  int tid = threadIdx.x, lane = tid & 63, wid = tid >> 6;
  int wr = wid >> 1, wc = wid & 1;
  int lr = lane >> 2, lk = (lane & 3) * 8;
  int kg = (lane >> 4) * 8, fr = lane & 15;
  f32x4 acc[4][4] = {};

  for (int t = 0; t < 10; ++t) {
    int k0 = t * 32;
    for (int c = wid * 2; c < wid * 2 + 2; ++c) {
      int row = rowBase + c * 16 + lr; if (row > 299) row = 299;
      glds16(Pb + (size_t)row * SP + k0 + lk, &As[c * 512 + lane * 8]);
    }
    for (int c = wid * 2; c < wid * 2 + 2; ++c)
      glds16(Vtb + (size_t)(n0 + c * 16 + lr) * SP + k0 + lk,
             &Bs[c * 512 + lane * 8]);
    __syncthreads();
    SB8 aF[4], bF[4];
#pragma unroll
    for (int m = 0; m < 4; ++m)
      aF[m].s = *(const s16x8*)&As[(wr * 64 + m * 16 + fr) * 32 + kg];
#pragma unroll
    for (int n = 0; n < 4; ++n)
      bF[n].s = *(const s16x8*)&Bs[(wc * 64 + n * 16 + fr) * 32 + kg];
#pragma unroll
    for (int m = 0; m < 4; ++m)
#pragma unroll
      for (int n = 0; n < 4; ++n)
        acc[m][n] = __builtin_amdgcn_mfma_f32_16x16x32_bf16(aF[m].b, bF[n].b, acc[m][n], 0, 0, 0);
    __syncthreads();
  }
  int fq = lane >> 4;
#pragma unroll
  for (int m = 0; m < 4; ++m)
#pragma unroll
    for (int n = 0; n < 4; ++n) {
      int col = n0 + wc * 64 + n * 16 + fr;
#pragma unroll
      for (int jj = 0; jj < 4; ++jj) {
        int row = rowBase + wr * 64 + m * 16 + fq * 4 + jj;
        if (row < 300) Ob[(size_t)row * 512 + col] = acc[m][n][jj];
      }
    }
}

// ---- launcher -------------------------------------------------------------
extern "C" void kernel_launch(void* const* d_in, const int* in_sizes, int n_in,
                              void* d_out, int out_size, void* d_ws, size_t ws_size,
                              hipStream_t stream) {
  const float* x = (const float*)d_in[0];
  const float* w = (const float*)d_in[1];
  float* out = (float*)d_out;
  char* ws = (char*)d_ws;
  // layout (bytes):
  //   Q  @ 0           (78,643,200)
  //   K  @ 78,643,200  (78,643,200)
  //   V  @ 157,286,400 (78,643,200)
  //   xb @ 235,929,600 (78,643,200)   -- dead after k_proj
  //   P  @ 235,929,600 (49,152,000)   -- aliases xb, written by k_attn_p
  //   Vt @ 0           (83,886,080)   -- aliases Q + K-head, written after k_attn_p
  //   Wt @ 314,572,800 (1,572,864)    -- total 316,145,664 B
  unsigned short* Q  = (unsigned short*)(ws);
  unsigned short* xb = (unsigned short*)(ws + 235929600LL);
  unsigned short* Pp = (unsigned short*)(ws + 235929600LL);
  unsigned short* Vt = (unsigned short*)(ws);
  unsigned short* Wt = (unsigned short*)(ws + 314572800LL);
  unsigned short* Kk = (unsigned short*)(ws + 78643200LL);
  unsigned short* Vv = (unsigned short*)(ws + 157286400LL);

  k_cvt_x<<<2048, 256, 0, stream>>>(x, xb, 4915200);
  k_wt<<<3072, 256, 0, stream>>>(w, Wt);
  k_proj<<<7200, 256, 0, stream>>>(xb, Wt, Q);          // writes Q,K,V (contiguous)
  k_attn_p<<<dim3(256, 10), 256, 0, stream>>>(Q, Kk, Pp);
  k_vt<<<dim3(10, 16, 256), 256, 0, stream>>>(Vv, Vt);  // Vt overwrites Q/K (dead)
  k_pv<<<3072, 256, 0, stream>>>(Pp, Vt, out);
}

// Round 2
// 1285.234 us; speedup vs baseline: 1.1090x; 1.1090x over previous
//
#include <hip/hip_runtime.h>
#include <hip/hip_bf16.h>
#include <math.h>

// ---- types ----------------------------------------------------------------
typedef __attribute__((ext_vector_type(8))) __bf16 bf16x8;
typedef __attribute__((ext_vector_type(8))) short  s16x8;
typedef __attribute__((ext_vector_type(4))) float  f32x4;
union SB8 { s16x8 s; bf16x8 b; };

__device__ __forceinline__ unsigned short f2bf(float f) {
  unsigned int u = __builtin_bit_cast(unsigned int, f);
  u = u + 0x7FFFu + ((u >> 16) & 1u);           // round-to-nearest-even
  return (unsigned short)(u >> 16);
}

// async global->LDS, 16B per lane; LDS dest = wave-uniform base + lane*16
__device__ __forceinline__ void glds16(const void* g, void* l) {
  __builtin_amdgcn_global_load_lds((const __attribute__((address_space(1))) void*)g,
                                   (__attribute__((address_space(3))) void*)l, 16, 0, 0);
}

#define B_  256
#define S_  300
#define D_  512
#define SP  320          // keys padded to 320 (zero pad)
#define M_  76800        // B_*S_

// ---- K0: x fp32 -> bf16 (vectorized, 8 elems/iter) ------------------------
__global__ __launch_bounds__(256) void k_cvt_x(const float* __restrict__ x,
                                               unsigned short* __restrict__ xb, int n8) {
  int i = blockIdx.x * blockDim.x + threadIdx.x;
  int stride = gridDim.x * blockDim.x;
  for (; i < n8; i += stride) {
    const float4* p = (const float4*)(x + (size_t)i * 8);
    float4 a = p[0], b = p[1];
    union { unsigned short u[8]; s16x8 v; } o;
    o.u[0]=f2bf(a.x); o.u[1]=f2bf(a.y); o.u[2]=f2bf(a.z); o.u[3]=f2bf(a.w);
    o.u[4]=f2bf(b.x); o.u[5]=f2bf(b.y); o.u[6]=f2bf(b.z); o.u[7]=f2bf(b.w);
    *(s16x8*)(xb + (size_t)i * 8) = o.v;
  }
}

// ---- K0b: W[3][512][512] -> Wt[3][512][512] (n-major) bf16 ----------------
__global__ __launch_bounds__(256) void k_wt(const float* __restrict__ w,
                                            unsigned short* __restrict__ wt) {
  int i = blockIdx.x * 256 + threadIdx.x;       // exactly 3*512*512 threads
  int p = i >> 18;
  int r = i & 262143;
  int k = r >> 9, n = r & 511;
  wt[p * 262144 + n * 512 + k] = f2bf(w[i]);
}

// ---- K1: QKV projection GEMM (m97 structure: 128x128, BK=32, 4 waves) -----
// A = x_bf16 [76800][512], B^T = Wt[p] [512][512], C -> bf16 Q/K/V
__global__ __launch_bounds__(256) void k_proj(const unsigned short* __restrict__ xb,
                                              const unsigned short* __restrict__ wt,
                                              unsigned short* __restrict__ qkv) {
  __shared__ short As[128 * 32];
  __shared__ short Bs[128 * 32];
  // XCD-bijective swizzle: 7200 = 8 * 900, 900 = 75 * 12; colocate the 12
  // (n0,p) blocks sharing one 128-row x-panel on one XCD.
  int bid = blockIdx.x;
  int xc = bid & 7, j = bid >> 3;
  int mt = xc + 8 * (j / 12);
  int tile = j % 12;
  int n0 = (tile & 3) * 128;
  int p  = tile >> 2;
  int rowBase = mt * 128;
  const unsigned short* wp = wt + p * 262144;
  unsigned short* outp = qkv + (size_t)p * ((size_t)M_ * 512);

  int tid = threadIdx.x, lane = tid & 63, wid = tid >> 6;
  int wr = wid >> 1, wc = wid & 1;
  int lr = lane >> 2, lk = (lane & 3) * 8;      // staging: row-in-chunk, k-off
  int kg = (lane >> 4) * 8, fr = lane & 15;     // fragment indices
  f32x4 acc[4][4] = {};

  for (int t = 0; t < 16; ++t) {
    int k0 = t * 32;
    for (int c = wid * 2; c < wid * 2 + 2; ++c)   // A: 8 chunks of 1KB
      glds16(xb + (size_t)(rowBase + c * 16 + lr) * 512 + k0 + lk,
             &As[c * 512 + lane * 8]);
    for (int c = wid * 2; c < wid * 2 + 2; ++c)   // B
      glds16(wp + (size_t)(n0 + c * 16 + lr) * 512 + k0 + lk,
             &Bs[c * 512 + lane * 8]);
    __syncthreads();
    SB8 aF[4], bF[4];
#pragma unroll
    for (int m = 0; m < 4; ++m)
      aF[m].s = *(const s16x8*)&As[(wr * 64 + m * 16 + fr) * 32 + kg];
#pragma unroll
    for (int n = 0; n < 4; ++n)
      bF[n].s = *(const s16x8*)&Bs[(wc * 64 + n * 16 + fr) * 32 + kg];
#pragma unroll
    for (int m = 0; m < 4; ++m)
#pragma unroll
      for (int n = 0; n < 4; ++n)
        acc[m][n] = __builtin_amdgcn_mfma_f32_16x16x32_bf16(aF[m].b, bF[n].b, acc[m][n], 0, 0, 0);
    __syncthreads();
  }
  int fq = lane >> 4;
#pragma unroll
  for (int m = 0; m < 4; ++m)
#pragma unroll
    for (int n = 0; n < 4; ++n) {
      int row = rowBase + wr * 64 + m * 16 + fq * 4;
      int col = n0 + wc * 64 + n * 16 + fr;
      unsigned short* o = outp + (size_t)row * 512 + col;
#pragma unroll
      for (int jj = 0; jj < 4; ++jj)
        o[(size_t)jj * 512] = f2bf(acc[m][n][jj]);
    }
}

// ---- K2: P = softmax(Q K^T / sqrt(300)) per (batch, 32-row q-tile) --------
// v2: XCD swizzle (10 q-tiles of a batch colocated -> K is L2-resident) +
// coalesced vectorized P write (kills the 2.4 GB sector-write amplification).
__global__ __launch_bounds__(256) void k_attn_p(const unsigned short* __restrict__ Q,
                                                const unsigned short* __restrict__ K,
                                                unsigned short* __restrict__ P) {
  __shared__ union {
    struct { short q[32 * 512]; short k[304 * 32]; } s1;   // 52224 B
    float S[32 * 321];                                     // 41088 B
  } sm;
  __shared__ float invS[32];
  // grid = 2560: xcd = bid&7, slot = bid>>3 (0..319) = 32 batches x 10 qtiles
  int bid = blockIdx.x;
  int xcd = bid & 7, slot = bid >> 3;
  int b = xcd * 32 + slot / 10;
  int qt = slot % 10;
  int qBase = qt * 32;
  const unsigned short* Qb = Q + (size_t)b * S_ * 512;
  const unsigned short* Kb = K + (size_t)b * S_ * 512;
  unsigned short* Pb = P + (size_t)b * S_ * SP;
  int tid = threadIdx.x, lane = tid & 63, wid = tid >> 6;
  int lr = lane >> 2, lk = (lane & 3) * 8;
  int kg = (lane >> 4) * 8, fr = lane & 15;

  // stage Q once (32 chunks = 32 rows); source pre-swizzled so LDS holds
  // content[r][p] = Q[r][p ^ ((r&7)*8)]
  for (int c = wid * 8; c < wid * 8 + 8; ++c) {
    int qr = qBase + c; if (qr > 299) qr = 299;
    int ke = (lane * 8) ^ ((c & 7) * 8);
    glds16(Qb + (size_t)qr * 512 + ke, &sm.s1.q[c * 512 + lane * 8]);
  }
  int ntBase = (wid < 3) ? wid * 5 : 15;
  int ntCnt  = (wid < 3) ? 5 : 4;
  f32x4 acc[2][5] = {};

  for (int t = 0; t < 16; ++t) {
    int k0 = t * 32;
    for (int c = wid; c < 19; c += 4) {          // K tile [304][32]
      int kr = c * 16 + lr; if (kr > 299) kr = 299;
      glds16(Kb + (size_t)kr * 512 + k0 + lk, &sm.s1.k[c * 512 + lane * 8]);
    }
    __syncthreads();
    SB8 qF[2], kF[5];
#pragma unroll
    for (int m = 0; m < 2; ++m) {
      int r = m * 16 + fr;
      int ko = (k0 + kg) ^ ((r & 7) * 8);        // swizzled read
      qF[m].s = *(const s16x8*)&sm.s1.q[r * 512 + ko];
    }
    for (int n = 0; n < ntCnt; ++n)
      kF[n].s = *(const s16x8*)&sm.s1.k[((ntBase + n) * 16 + fr) * 32 + kg];
#pragma unroll
    for (int m = 0; m < 2; ++m)
      for (int n = 0; n < ntCnt; ++n)
        acc[m][n] = __builtin_amdgcn_mfma_f32_16x16x32_bf16(qF[m].b, kF[n].b, acc[m][n], 0, 0, 0);
    __syncthreads();
  }

  // spill scores to LDS (scaled)
  const float scale = 0.05773502691896258f;      // 1/sqrt(300)
  for (int m = 0; m < 2; ++m)
    for (int n = 0; n < ntCnt; ++n) {
      int col = (ntBase + n) * 16 + fr;
      int rb = m * 16 + (lane >> 4) * 4;
#pragma unroll
      for (int jj = 0; jj < 4; ++jj)
        sm.S[(rb + jj) * 321 + col] = acc[m][n][jj] * scale;
    }
  __syncthreads();

  // wave-parallel softmax: 8 threads per row; leave exp in LDS, inv in invS
  {
    int r = tid >> 3, jj = tid & 7;
    int c0 = jj * 38, c1 = c0 + 38; if (c1 > 300) c1 = 300;
    float mx = -1e30f;
    for (int c = c0; c < c1; ++c) mx = fmaxf(mx, sm.S[r * 321 + c]);
    mx = fmaxf(mx, __shfl_xor(mx, 1));
    mx = fmaxf(mx, __shfl_xor(mx, 2));
    mx = fmaxf(mx, __shfl_xor(mx, 4));
    float sum = 0.f;
    for (int c = c0; c < c1; ++c) {
      float e = __expf(sm.S[r * 321 + c] - mx);
      sm.S[r * 321 + c] = e; sum += e;
    }
    sum += __shfl_xor(sum, 1);
    sum += __shfl_xor(sum, 2);
    sum += __shfl_xor(sum, 4);
    if (jj == 0) invS[r] = 1.0f / sum;
  }
  __syncthreads();

  // coalesced P write: consecutive threads -> consecutive 16B chunks.
  // 32 rows x 40 segs of 8 ushorts = 1280 units, 5 iters of 256 threads.
  for (int idx = tid; idx < 32 * 40; idx += 256) {
    int r = idx / 40, seg = idx - r * 40;
    int qrow = qBase + r;
    if (qrow >= 300) continue;
    float inv = invS[r];
    int cb = seg * 8;
    union { unsigned short u[8]; s16x8 v; } o;
#pragma unroll
    for (int j = 0; j < 8; ++j) {
      int c = cb + j;
      o.u[j] = (c < 300) ? f2bf(sm.S[r * 321 + c] * inv) : (unsigned short)0;
    }
    *(s16x8*)(Pb + (size_t)qrow * SP + cb) = o.v;
  }
}

// ---- K1b: V [B][300][512] -> Vt [B][512][320] bf16, zero-padded -----------
__global__ __launch_bounds__(256) void k_vt(const unsigned short* __restrict__ V,
                                            unsigned short* __restrict__ Vt) {
  __shared__ unsigned short tile[32][33];
  int kt = blockIdx.x, nt = blockIdx.y, b = blockIdx.z;
  const unsigned short* Vb = V + (size_t)b * S_ * 512;
  unsigned short* Vtb = Vt + (size_t)b * 512 * SP;
  int tc = threadIdx.x & 31, tr = threadIdx.x >> 5;   // tr 0..7
#pragma unroll
  for (int i = 0; i < 4; ++i) {
    int k = kt * 32 + tr + i * 8;
    int n = nt * 32 + tc;
    tile[tr + i * 8][tc] = (k < 300) ? Vb[(size_t)k * 512 + n] : (unsigned short)0;
  }
  __syncthreads();
#pragma unroll
  for (int i = 0; i < 4; ++i) {
    int n = nt * 32 + tr + i * 8;
    int k = kt * 32 + tc;
    Vtb[(size_t)n * SP + k] = tile[tc][tr + i * 8];
  }
}

// ---- K3: O = P @ V  (A = P [300][320], B^T = Vt [512][320], C fp32) -------
__global__ __launch_bounds__(256) void k_pv(const unsigned short* __restrict__ P,
                                            const unsigned short* __restrict__ Vt,
                                            float* __restrict__ O) {
  __shared__ short As[128 * 32];
  __shared__ short Bs[128 * 32];
  int bid = blockIdx.x;                       // 3072 = 8*384, 384 = 32*12
  int xc = bid & 7, j = bid >> 3;
  int b = xc + 8 * (j / 12);
  int tile = j % 12;
  int mt = tile >> 2, n0 = (tile & 3) * 128;
  int rowBase = mt * 128;
  const unsigned short* Pb  = P  + (size_t)b * S_ * SP;
  const unsigned short* Vtb = Vt + (size_t)b * 512 * SP;
  float* Ob = O + (size_t)b * S_ * 512;
  int tid = threadIdx.x, lane = tid & 63, wid = tid >> 6;
  int wr = wid >> 1, wc = wid & 1;
  int lr = lane >> 2, lk = (lane & 3) * 8;
  int kg = (lane >> 4) * 8, fr = lane & 15;
  f32x4 acc[4][4] = {};

  for (int t = 0; t < 10; ++t) {
    int k0 = t * 32;
    for (int c = wid * 2; c < wid * 2 + 2; ++c) {
      int row = rowBase + c * 16 + lr; if (row > 299) row = 299;
      glds16(Pb + (size_t)row * SP + k0 + lk, &As[c * 512 + lane * 8]);
    }
    for (int c = wid * 2; c < wid * 2 + 2; ++c)
      glds16(Vtb + (size_t)(n0 + c * 16 + lr) * SP + k0 + lk,
             &Bs[c * 512 + lane * 8]);
    __syncthreads();
    SB8 aF[4], bF[4];
#pragma unroll
    for (int m = 0; m < 4; ++m)
      aF[m].s = *(const s16x8*)&As[(wr * 64 + m * 16 + fr) * 32 + kg];
#pragma unroll
    for (int n = 0; n < 4; ++n)
      bF[n].s = *(const s16x8*)&Bs[(wc * 64 + n * 16 + fr) * 32 + kg];
#pragma unroll
    for (int m = 0; m < 4; ++m)
#pragma unroll
      for (int n = 0; n < 4; ++n)
        acc[m][n] = __builtin_amdgcn_mfma_f32_16x16x32_bf16(aF[m].b, bF[n].b, acc[m][n], 0, 0, 0);
    __syncthreads();
  }
  int fq = lane >> 4;
#pragma unroll
  for (int m = 0; m < 4; ++m)
#pragma unroll
    for (int n = 0; n < 4; ++n) {
      int col = n0 + wc * 64 + n * 16 + fr;
#pragma unroll
      for (int jj = 0; jj < 4; ++jj) {
        int row = rowBase + wr * 64 + m * 16 + fq * 4 + jj;
        if (row < 300) Ob[(size_t)row * 512 + col] = acc[m][n][jj];
      }
    }
}

// ---- launcher -------------------------------------------------------------
extern "C" void kernel_launch(void* const* d_in, const int* in_sizes, int n_in,
                              void* d_out, int out_size, void* d_ws, size_t ws_size,
                              hipStream_t stream) {
  const float* x = (const float*)d_in[0];
  const float* w = (const float*)d_in[1];
  float* out = (float*)d_out;
  char* ws = (char*)d_ws;
  // layout (bytes):
  //   Q  @ 0           (78,643,200)
  //   K  @ 78,643,200  (78,643,200)
  //   V  @ 157,286,400 (78,643,200)
  //   xb @ 235,929,600 (78,643,200)   -- dead after k_proj
  //   P  @ 235,929,600 (49,152,000)   -- aliases xb, written by k_attn_p
  //   Vt @ 0           (83,886,080)   -- aliases Q + K-head, written after k_attn_p
  //   Wt @ 314,572,800 (1,572,864)    -- total 316,145,664 B
  unsigned short* Q  = (unsigned short*)(ws);
  unsigned short* xb = (unsigned short*)(ws + 235929600LL);
  unsigned short* Pp = (unsigned short*)(ws + 235929600LL);
  unsigned short* Vt = (unsigned short*)(ws);
  unsigned short* Wt = (unsigned short*)(ws + 314572800LL);
  unsigned short* Kk = (unsigned short*)(ws + 78643200LL);
  unsigned short* Vv = (unsigned short*)(ws + 157286400LL);

  k_cvt_x<<<2048, 256, 0, stream>>>(x, xb, 4915200);
  k_wt<<<3072, 256, 0, stream>>>(w, Wt);
  k_proj<<<7200, 256, 0, stream>>>(xb, Wt, Q);          // writes Q,K,V (contiguous)
  k_attn_p<<<2560, 256, 0, stream>>>(Q, Kk, Pp);
  k_vt<<<dim3(10, 16, 256), 256, 0, stream>>>(Vv, Vt);  // Vt overwrites Q/K (dead)
  k_pv<<<3072, 256, 0, stream>>>(Pp, Vt, out);
}

// Round 3
// 532.278 us; speedup vs baseline: 2.6779x; 2.4146x over previous
//
#include <hip/hip_runtime.h>
#include <hip/hip_bf16.h>
#include <math.h>

// ---- types ----------------------------------------------------------------
typedef __attribute__((ext_vector_type(8))) __bf16 bf16x8;
typedef __attribute__((ext_vector_type(8))) short  s16x8;
typedef __attribute__((ext_vector_type(4))) float  f32x4;
union SB8 { s16x8 s; bf16x8 b; };

__device__ __forceinline__ unsigned short f2bf(float f) {
  unsigned int u = __builtin_bit_cast(unsigned int, f);
  u = u + 0x7FFFu + ((u >> 16) & 1u);           // round-to-nearest-even
  return (unsigned short)(u >> 16);
}

// async global->LDS, 16B per lane; LDS dest = wave-uniform base + lane*16
__device__ __forceinline__ void glds16(const void* g, void* l) {
  __builtin_amdgcn_global_load_lds((const __attribute__((address_space(1))) void*)g,
                                   (__attribute__((address_space(3))) void*)l, 16, 0, 0);
}

#define B_  256
#define S_  300
#define D_  512
#define SP  320          // keys padded to 320 (zero pad)
#define M_  76800        // B_*S_

// ---- K0: x fp32 -> bf16 (vectorized, 8 elems/iter) ------------------------
__global__ __launch_bounds__(256) void k_cvt_x(const float* __restrict__ x,
                                               unsigned short* __restrict__ xb, int n8) {
  int i = blockIdx.x * blockDim.x + threadIdx.x;
  int stride = gridDim.x * blockDim.x;
  for (; i < n8; i += stride) {
    const float4* p = (const float4*)(x + (size_t)i * 8);
    float4 a = p[0], b = p[1];
    union { unsigned short u[8]; s16x8 v; } o;
    o.u[0]=f2bf(a.x); o.u[1]=f2bf(a.y); o.u[2]=f2bf(a.z); o.u[3]=f2bf(a.w);
    o.u[4]=f2bf(b.x); o.u[5]=f2bf(b.y); o.u[6]=f2bf(b.z); o.u[7]=f2bf(b.w);
    *(s16x8*)(xb + (size_t)i * 8) = o.v;
  }
}

// ---- K0b: W[3][512][512] -> Wt[3][512][512] (n-major) bf16 ----------------
__global__ __launch_bounds__(256) void k_wt(const float* __restrict__ w,
                                            unsigned short* __restrict__ wt) {
  int i = blockIdx.x * 256 + threadIdx.x;       // exactly 3*512*512 threads
  int p = i >> 18;
  int r = i & 262143;
  int k = r >> 9, n = r & 511;
  wt[p * 262144 + n * 512 + k] = f2bf(w[i]);
}

// ---- K1: QKV projection GEMM (m97 structure: 128x128, BK=32, 4 waves) -----
// A = x_bf16 [76800][512], B^T = Wt[p] [512][512], C -> bf16 Q/K/V
__global__ __launch_bounds__(256) void k_proj(const unsigned short* __restrict__ xb,
                                              const unsigned short* __restrict__ wt,
                                              unsigned short* __restrict__ qkv) {
  __shared__ short As[128 * 32];
  __shared__ short Bs[128 * 32];
  // XCD-bijective swizzle: 7200 = 8 * 900, 900 = 75 * 12; colocate the 12
  // (n0,p) blocks sharing one 128-row x-panel on one XCD.
  int bid = blockIdx.x;
  int xc = bid & 7, j = bid >> 3;
  int mt = xc + 8 * (j / 12);
  int tile = j % 12;
  int n0 = (tile & 3) * 128;
  int p  = tile >> 2;
  int rowBase = mt * 128;
  const unsigned short* wp = wt + p * 262144;
  unsigned short* outp = qkv + (size_t)p * ((size_t)M_ * 512);

  int tid = threadIdx.x, lane = tid & 63, wid = tid >> 6;
  int wr = wid >> 1, wc = wid & 1;
  int lr = lane >> 2, lk = (lane & 3) * 8;      // staging: row-in-chunk, k-off
  int kg = (lane >> 4) * 8, fr = lane & 15;     // fragment indices
  f32x4 acc[4][4] = {};

  for (int t = 0; t < 16; ++t) {
    int k0 = t * 32;
    for (int c = wid * 2; c < wid * 2 + 2; ++c)   // A: 8 chunks of 1KB
      glds16(xb + (size_t)(rowBase + c * 16 + lr) * 512 + k0 + lk,
             &As[c * 512 + lane * 8]);
    for (int c = wid * 2; c < wid * 2 + 2; ++c)   // B
      glds16(wp + (size_t)(n0 + c * 16 + lr) * 512 + k0 + lk,
             &Bs[c * 512 + lane * 8]);
    __syncthreads();
    SB8 aF[4], bF[4];
#pragma unroll
    for (int m = 0; m < 4; ++m)
      aF[m].s = *(const s16x8*)&As[(wr * 64 + m * 16 + fr) * 32 + kg];
#pragma unroll
    for (int n = 0; n < 4; ++n)
      bF[n].s = *(const s16x8*)&Bs[(wc * 64 + n * 16 + fr) * 32 + kg];
#pragma unroll
    for (int m = 0; m < 4; ++m)
#pragma unroll
      for (int n = 0; n < 4; ++n)
        acc[m][n] = __builtin_amdgcn_mfma_f32_16x16x32_bf16(aF[m].b, bF[n].b, acc[m][n], 0, 0, 0);
    __syncthreads();
  }
  int fq = lane >> 4;
#pragma unroll
  for (int m = 0; m < 4; ++m)
#pragma unroll
    for (int n = 0; n < 4; ++n) {
      int row = rowBase + wr * 64 + m * 16 + fq * 4;
      int col = n0 + wc * 64 + n * 16 + fr;
      unsigned short* o = outp + (size_t)row * 512 + col;
#pragma unroll
      for (int jj = 0; jj < 4; ++jj)
        o[(size_t)jj * 512] = f2bf(acc[m][n][jj]);
    }
}

// ---- K2: P = softmax(Q K^T / sqrt(300)) per (batch, 32-row q-tile) --------
// v3: STATIC tile counts (5 per wave, K padded to 320 rows) so acc[2][5] and
// kF[5] stay in registers. v2's runtime ntCnt put them in scratch -> 2.4 GB
// of spill traffic (rule #20). Cols 300-319 are garbage, masked downstream.
__global__ __launch_bounds__(256) void k_attn_p(const unsigned short* __restrict__ Q,
                                                const unsigned short* __restrict__ K,
                                                unsigned short* __restrict__ P) {
  __shared__ union {
    struct { short q[32 * 512]; short k[320 * 32]; } s1;   // 32KB + 20KB
    float S[32 * 321];                                     // 41088 B
  } sm;
  __shared__ float invS[32];
  // grid = 2560: xcd = bid&7, slot = bid>>3 (0..319) = 32 batches x 10 qtiles
  int bid = blockIdx.x;
  int xcd = bid & 7, slot = bid >> 3;
  int b = xcd * 32 + slot / 10;
  int qt = slot % 10;
  int qBase = qt * 32;
  const unsigned short* Qb = Q + (size_t)b * S_ * 512;
  const unsigned short* Kb = K + (size_t)b * S_ * 512;
  unsigned short* Pb = P + (size_t)b * S_ * SP;
  int tid = threadIdx.x, lane = tid & 63, wid = tid >> 6;
  int lr = lane >> 2, lk = (lane & 3) * 8;
  int kg = (lane >> 4) * 8, fr = lane & 15;

  // stage Q once (32 chunks = 32 rows); source pre-swizzled so LDS holds
  // content[r][p] = Q[r][p ^ ((r&7)*8)]
  for (int c = wid * 8; c < wid * 8 + 8; ++c) {
    int qr = qBase + c; if (qr > 299) qr = 299;
    int ke = (lane * 8) ^ ((c & 7) * 8);
    glds16(Qb + (size_t)qr * 512 + ke, &sm.s1.q[c * 512 + lane * 8]);
  }
  int ntBase = wid * 5;                          // static: 5 tiles per wave
  f32x4 acc[2][5] = {};

  for (int t = 0; t < 16; ++t) {
    int k0 = t * 32;
    for (int c = wid; c < 20; c += 4) {          // K tile [320][32], 20 chunks
      int kr = c * 16 + lr; if (kr > 299) kr = 299;
      glds16(Kb + (size_t)kr * 512 + k0 + lk, &sm.s1.k[c * 512 + lane * 8]);
    }
    __syncthreads();
    SB8 qF[2], kF[5];
#pragma unroll
    for (int m = 0; m < 2; ++m) {
      int r = m * 16 + fr;
      int ko = (k0 + kg) ^ ((r & 7) * 8);        // swizzled read
      qF[m].s = *(const s16x8*)&sm.s1.q[r * 512 + ko];
    }
#pragma unroll
    for (int n = 0; n < 5; ++n)
      kF[n].s = *(const s16x8*)&sm.s1.k[((ntBase + n) * 16 + fr) * 32 + kg];
#pragma unroll
    for (int m = 0; m < 2; ++m)
#pragma unroll
      for (int n = 0; n < 5; ++n)
        acc[m][n] = __builtin_amdgcn_mfma_f32_16x16x32_bf16(qF[m].b, kF[n].b, acc[m][n], 0, 0, 0);
    __syncthreads();
  }

  // spill scores to LDS (scaled); cols 300-319 garbage (never read)
  const float scale = 0.05773502691896258f;      // 1/sqrt(300)
#pragma unroll
  for (int m = 0; m < 2; ++m)
#pragma unroll
    for (int n = 0; n < 5; ++n) {
      int col = (ntBase + n) * 16 + fr;
      int rb = m * 16 + (lane >> 4) * 4;
#pragma unroll
      for (int jj = 0; jj < 4; ++jj)
        sm.S[(rb + jj) * 321 + col] = acc[m][n][jj] * scale;
    }
  __syncthreads();

  // wave-parallel softmax: 8 threads per row; leave exp in LDS, inv in invS
  {
    int r = tid >> 3, jj = tid & 7;
    int c0 = jj * 38, c1 = c0 + 38; if (c1 > 300) c1 = 300;
    float mx = -1e30f;
    for (int c = c0; c < c1; ++c) mx = fmaxf(mx, sm.S[r * 321 + c]);
    mx = fmaxf(mx, __shfl_xor(mx, 1));
    mx = fmaxf(mx, __shfl_xor(mx, 2));
    mx = fmaxf(mx, __shfl_xor(mx, 4));
    float sum = 0.f;
    for (int c = c0; c < c1; ++c) {
      float e = __expf(sm.S[r * 321 + c] - mx);
      sm.S[r * 321 + c] = e; sum += e;
    }
    sum += __shfl_xor(sum, 1);
    sum += __shfl_xor(sum, 2);
    sum += __shfl_xor(sum, 4);
    if (jj == 0) invS[r] = 1.0f / sum;
  }
  __syncthreads();

  // coalesced P write: consecutive threads -> consecutive 16B chunks.
  // 32 rows x 40 segs of 8 ushorts = 1280 units, 5 iters of 256 threads.
  for (int idx = tid; idx < 32 * 40; idx += 256) {
    int r = idx / 40, seg = idx - r * 40;
    int qrow = qBase + r;
    if (qrow >= 300) continue;
    float inv = invS[r];
    int cb = seg * 8;
    union { unsigned short u[8]; s16x8 v; } o;
#pragma unroll
    for (int j = 0; j < 8; ++j) {
      int c = cb + j;
      o.u[j] = (c < 300) ? f2bf(sm.S[r * 321 + c] * inv) : (unsigned short)0;
    }
    *(s16x8*)(Pb + (size_t)qrow * SP + cb) = o.v;
  }
}

// ---- K1b: V [B][300][512] -> Vt [B][512][320] bf16, zero-padded -----------
__global__ __launch_bounds__(256) void k_vt(const unsigned short* __restrict__ V,
                                            unsigned short* __restrict__ Vt) {
  __shared__ unsigned short tile[32][33];
  int kt = blockIdx.x, nt = blockIdx.y, b = blockIdx.z;
  const unsigned short* Vb = V + (size_t)b * S_ * 512;
  unsigned short* Vtb = Vt + (size_t)b * 512 * SP;
  int tc = threadIdx.x & 31, tr = threadIdx.x >> 5;   // tr 0..7
#pragma unroll
  for (int i = 0; i < 4; ++i) {
    int k = kt * 32 + tr + i * 8;
    int n = nt * 32 + tc;
    tile[tr + i * 8][tc] = (k < 300) ? Vb[(size_t)k * 512 + n] : (unsigned short)0;
  }
  __syncthreads();
#pragma unroll
  for (int i = 0; i < 4; ++i) {
    int n = nt * 32 + tr + i * 8;
    int k = kt * 32 + tc;
    Vtb[(size_t)n * SP + k] = tile[tc][tr + i * 8];
  }
}

// ---- K3: O = P @ V  (A = P [300][320], B^T = Vt [512][320], C fp32) -------
__global__ __launch_bounds__(256) void k_pv(const unsigned short* __restrict__ P,
                                            const unsigned short* __restrict__ Vt,
                                            float* __restrict__ O) {
  __shared__ short As[128 * 32];
  __shared__ short Bs[128 * 32];
  int bid = blockIdx.x;                       // 3072 = 8*384, 384 = 32*12
  int xc = bid & 7, j = bid >> 3;
  int b = xc + 8 * (j / 12);
  int tile = j % 12;
  int mt = tile >> 2, n0 = (tile & 3) * 128;
  int rowBase = mt * 128;
  const unsigned short* Pb  = P  + (size_t)b * S_ * SP;
  const unsigned short* Vtb = Vt + (size_t)b * 512 * SP;
  float* Ob = O + (size_t)b * S_ * 512;
  int tid = threadIdx.x, lane = tid & 63, wid = tid >> 6;
  int wr = wid >> 1, wc = wid & 1;
  int lr = lane >> 2, lk = (lane & 3) * 8;
  int kg = (lane >> 4) * 8, fr = lane & 15;
  f32x4 acc[4][4] = {};

  for (int t = 0; t < 10; ++t) {
    int k0 = t * 32;
    for (int c = wid * 2; c < wid * 2 + 2; ++c) {
      int row = rowBase + c * 16 + lr; if (row > 299) row = 299;
      glds16(Pb + (size_t)row * SP + k0 + lk, &As[c * 512 + lane * 8]);
    }
    for (int c = wid * 2; c < wid * 2 + 2; ++c)
      glds16(Vtb + (size_t)(n0 + c * 16 + lr) * SP + k0 + lk,
             &Bs[c * 512 + lane * 8]);
    __syncthreads();
    SB8 aF[4], bF[4];
#pragma unroll
    for (int m = 0; m < 4; ++m)
      aF[m].s = *(const s16x8*)&As[(wr * 64 + m * 16 + fr) * 32 + kg];
#pragma unroll
    for (int n = 0; n < 4; ++n)
      bF[n].s = *(const s16x8*)&Bs[(wc * 64 + n * 16 + fr) * 32 + kg];
#pragma unroll
    for (int m = 0; m < 4; ++m)
#pragma unroll
      for (int n = 0; n < 4; ++n)
        acc[m][n] = __builtin_amdgcn_mfma_f32_16x16x32_bf16(aF[m].b, bF[n].b, acc[m][n], 0, 0, 0);
    __syncthreads();
  }
  int fq = lane >> 4;
#pragma unroll
  for (int m = 0; m < 4; ++m)
#pragma unroll
    for (int n = 0; n < 4; ++n) {
      int col = n0 + wc * 64 + n * 16 + fr;
#pragma unroll
      for (int jj = 0; jj < 4; ++jj) {
        int row = rowBase + wr * 64 + m * 16 + fq * 4 + jj;
        if (row < 300) Ob[(size_t)row * 512 + col] = acc[m][n][jj];
      }
    }
}

// ---- launcher -------------------------------------------------------------
extern "C" void kernel_launch(void* const* d_in, const int* in_sizes, int n_in,
                              void* d_out, int out_size, void* d_ws, size_t ws_size,
                              hipStream_t stream) {
  const float* x = (const float*)d_in[0];
  const float* w = (const float*)d_in[1];
  float* out = (float*)d_out;
  char* ws = (char*)d_ws;
  // layout (bytes):
  //   Q  @ 0           (78,643,200)
  //   K  @ 78,643,200  (78,643,200)
  //   V  @ 157,286,400 (78,643,200)
  //   xb @ 235,929,600 (78,643,200)   -- dead after k_proj
  //   P  @ 235,929,600 (49,152,000)   -- aliases xb, written by k_attn_p
  //   Vt @ 0           (83,886,080)   -- aliases Q + K-head, written after k_attn_p
  //   Wt @ 314,572,800 (1,572,864)    -- total 316,145,664 B
  unsigned short* Q  = (unsigned short*)(ws);
  unsigned short* xb = (unsigned short*)(ws + 235929600LL);
  unsigned short* Pp = (unsigned short*)(ws + 235929600LL);
  unsigned short* Vt = (unsigned short*)(ws);
  unsigned short* Wt = (unsigned short*)(ws + 314572800LL);
  unsigned short* Kk = (unsigned short*)(ws + 78643200LL);
  unsigned short* Vv = (unsigned short*)(ws + 157286400LL);

  k_cvt_x<<<2048, 256, 0, stream>>>(x, xb, 4915200);
  k_wt<<<3072, 256, 0, stream>>>(w, Wt);
  k_proj<<<7200, 256, 0, stream>>>(xb, Wt, Q);          // writes Q,K,V (contiguous)
  k_attn_p<<<2560, 256, 0, stream>>>(Q, Kk, Pp);
  k_vt<<<dim3(10, 16, 256), 256, 0, stream>>>(Vv, Vt);  // Vt overwrites Q/K (dead)
  k_pv<<<3072, 256, 0, stream>>>(Pp, Vt, out);
}

// Round 5
// 491.965 us; speedup vs baseline: 2.8973x; 1.0819x over previous
//
#include <hip/hip_runtime.h>
#include <hip/hip_bf16.h>
#include <math.h>

// ---- types ----------------------------------------------------------------
typedef __attribute__((ext_vector_type(8))) __bf16 bf16x8;
typedef __attribute__((ext_vector_type(8))) short  s16x8;
typedef __attribute__((ext_vector_type(4))) float  f32x4;
union SB8 { s16x8 s; bf16x8 b; };

__device__ __forceinline__ unsigned short f2bf(float f) {
  unsigned int u = __builtin_bit_cast(unsigned int, f);
  u = u + 0x7FFFu + ((u >> 16) & 1u);           // round-to-nearest-even
  return (unsigned short)(u >> 16);
}

// async global->LDS, 16B per lane; LDS dest = wave-uniform base + lane*16
__device__ __forceinline__ void glds16(const void* g, void* l) {
  __builtin_amdgcn_global_load_lds((const __attribute__((address_space(1))) void*)g,
                                   (__attribute__((address_space(3))) void*)l, 16, 0, 0);
}

#define B_  256
#define S_  300
#define D_  512
#define SP  320          // keys padded to 320 (zero pad)
#define M_  76800        // B_*S_

// ---- K0: x fp32 -> bf16 (vectorized, 8 elems/iter) ------------------------
__global__ __launch_bounds__(256) void k_cvt_x(const float* __restrict__ x,
                                               unsigned short* __restrict__ xb, int n8) {
  int i = blockIdx.x * blockDim.x + threadIdx.x;
  int stride = gridDim.x * blockDim.x;
  for (; i < n8; i += stride) {
    const float4* p = (const float4*)(x + (size_t)i * 8);
    float4 a = p[0], b = p[1];
    union { unsigned short u[8]; s16x8 v; } o;
    o.u[0]=f2bf(a.x); o.u[1]=f2bf(a.y); o.u[2]=f2bf(a.z); o.u[3]=f2bf(a.w);
    o.u[4]=f2bf(b.x); o.u[5]=f2bf(b.y); o.u[6]=f2bf(b.z); o.u[7]=f2bf(b.w);
    *(s16x8*)(xb + (size_t)i * 8) = o.v;
  }
}

// ---- K0b: W[3][512][512] -> Wt[3][512][512] (n-major) bf16 ----------------
__global__ __launch_bounds__(256) void k_wt(const float* __restrict__ w,
                                            unsigned short* __restrict__ wt) {
  int i = blockIdx.x * 256 + threadIdx.x;       // exactly 3*512*512 threads
  int p = i >> 18;
  int r = i & 262143;
  int k = r >> 9, n = r & 511;
  wt[p * 262144 + n * 512 + k] = f2bf(w[i]);
}

// ---- K1: QKV projection GEMM -----------------------------------------------
// v4: BK=64, double-buffered LDS, prefetch issued BEFORE compute (loads fly
// under the MFMAs), ONE __syncthreads per K-step (full drain -> race-free;
// the round-4 vmcnt-only barrier let in-flight ds_reads race the next
// prefetch). Fragment reads slot-XOR swizzled (rows are 128B -> 16-way bank
// conflict without it); source pre-swizzled so glds dest stays linear (m173).
__global__ __launch_bounds__(256) void k_proj(const unsigned short* __restrict__ xb,
                                              const unsigned short* __restrict__ wt,
                                              unsigned short* __restrict__ qkv) {
  __shared__ short As[2][128 * 64];   // 2 x 16 KB
  __shared__ short Bs[2][128 * 64];   // 2 x 16 KB
  int bid = blockIdx.x;
  int xc = bid & 7, j = bid >> 3;
  int mt = xc + 8 * (j / 12);
  int tile = j % 12;
  int n0 = (tile & 3) * 128;
  int p  = tile >> 2;
  int rowBase = mt * 128;
  const unsigned short* wp = wt + p * 262144;
  unsigned short* outp = qkv + (size_t)p * ((size_t)M_ * 512);

  int tid = threadIdx.x, lane = tid & 63, wid = tid >> 6;
  int wr = wid >> 1, wc = wid & 1;
  int sr = lane >> 3;                  // staging: row-in-chunk 0..7
  int ssg = ((lane & 7) ^ sr) * 8;     // pre-swizzled source slot (shorts)
  int fr = lane & 15;
  int g  = lane >> 4;                  // fragment k-slot group
  f32x4 acc[4][4] = {};

  // prologue: stage t=0 into buf 0
  for (int c = wid * 4; c < wid * 4 + 4; ++c) {
    glds16(xb + (size_t)(rowBase + c * 8 + sr) * 512 + ssg, &As[0][c * 512 + lane * 8]);
    glds16(wp + (size_t)(n0 + c * 8 + sr) * 512 + ssg, &Bs[0][c * 512 + lane * 8]);
  }
  __syncthreads();

  for (int t = 0; t < 8; ++t) {
    int cur = t & 1;
    if (t < 7) {
      int k0n = (t + 1) * 64;
      for (int c = wid * 4; c < wid * 4 + 4; ++c) {
        glds16(xb + (size_t)(rowBase + c * 8 + sr) * 512 + k0n + ssg,
               &As[cur ^ 1][c * 512 + lane * 8]);
        glds16(wp + (size_t)(n0 + c * 8 + sr) * 512 + k0n + ssg,
               &Bs[cur ^ 1][c * 512 + lane * 8]);
      }
    }
    SB8 aF[4][2], bF[4][2];
#pragma unroll
    for (int m = 0; m < 4; ++m) {
      int row = wr * 64 + m * 16 + fr;
#pragma unroll
      for (int kk = 0; kk < 2; ++kk) {
        int sl = ((kk << 2) + g) ^ (fr & 7);
        aF[m][kk].s = *(const s16x8*)&As[cur][row * 64 + sl * 8];
      }
    }
#pragma unroll
    for (int n = 0; n < 4; ++n) {
      int row = wc * 64 + n * 16 + fr;
#pragma unroll
      for (int kk = 0; kk < 2; ++kk) {
        int sl = ((kk << 2) + g) ^ (fr & 7);
        bF[n][kk].s = *(const s16x8*)&Bs[cur][row * 64 + sl * 8];
      }
    }
#pragma unroll
    for (int kk = 0; kk < 2; ++kk)
#pragma unroll
      for (int m = 0; m < 4; ++m)
#pragma unroll
        for (int n = 0; n < 4; ++n)
          acc[m][n] = __builtin_amdgcn_mfma_f32_16x16x32_bf16(aF[m][kk].b, bF[n][kk].b,
                                                              acc[m][n], 0, 0, 0);
    __syncthreads();
  }

  int fq = lane >> 4;
#pragma unroll
  for (int m = 0; m < 4; ++m)
#pragma unroll
    for (int n = 0; n < 4; ++n) {
      int row = rowBase + wr * 64 + m * 16 + fq * 4;
      int col = n0 + wc * 64 + n * 16 + fr;
      unsigned short* o = outp + (size_t)row * 512 + col;
#pragma unroll
      for (int jj = 0; jj < 4; ++jj)
        o[(size_t)jj * 512] = f2bf(acc[m][n][jj]);
    }
}

// ---- K2: P = softmax(Q K^T / sqrt(300)) per (batch, 32-row q-tile) --------
// v5: K dbuf + prefetch-before-compute with __syncthreads (full drain).
// K tile slot-swizzled (slot ^= row&3): kF read was a 16-way bank conflict
// (6.1e7 SQ_LDS_BANK_CONFLICT), now 4-way. Softmax 4-way unrolled; P write
// coalesced 16B/thread.
__global__ __launch_bounds__(256) void k_attn_p(const unsigned short* __restrict__ Q,
                                                const unsigned short* __restrict__ K,
                                                unsigned short* __restrict__ P) {
  __shared__ union {
    struct { short q[32 * 512]; short k[2][320 * 32]; } s1;  // 32 + 40 KB
    float S[32 * 321];                                       // 41088 B
  } sm;
  __shared__ float invS[32];
  // grid = 2560: xcd = bid&7, slot = bid>>3 (0..319) = 32 batches x 10 qtiles
  int bid = blockIdx.x;
  int xcd = bid & 7, slot = bid >> 3;
  int b = xcd * 32 + slot / 10;
  int qt = slot % 10;
  int qBase = qt * 32;
  const unsigned short* Qb = Q + (size_t)b * S_ * 512;
  const unsigned short* Kb = K + (size_t)b * S_ * 512;
  unsigned short* Pb = P + (size_t)b * S_ * SP;
  int tid = threadIdx.x, lane = tid & 63, wid = tid >> 6;
  int lr = lane >> 2;                            // K-stage row-in-chunk 0..15
  int sk = ((lane & 3) ^ (lr & 3)) * 8;          // pre-swizzled K source slot
  int kg = (lane >> 4) * 8, fr = lane & 15;
  int g = lane >> 4;

  // stage Q once (32 rows); source pre-swizzled: LDS[r][s] = Q[r][s^(r&7)]
  for (int c = wid * 8; c < wid * 8 + 8; ++c) {
    int qr = qBase + c; if (qr > 299) qr = 299;
    int ke = (lane * 8) ^ ((c & 7) * 8);
    glds16(Qb + (size_t)qr * 512 + ke, &sm.s1.q[c * 512 + lane * 8]);
  }
  // prologue: stage K slice t=0 into buf 0 (slot-swizzled source)
  for (int c = wid; c < 20; c += 4) {
    int kr = c * 16 + lr; if (kr > 299) kr = 299;
    glds16(Kb + (size_t)kr * 512 + sk, &sm.s1.k[0][c * 512 + lane * 8]);
  }
  __syncthreads();

  int ntBase = wid * 5;                          // static: 5 tiles per wave
  f32x4 acc[2][5] = {};

  for (int t = 0; t < 16; ++t) {
    int cur = t & 1;
    if (t < 15) {
      int k0n = (t + 1) * 32;
      for (int c = wid; c < 20; c += 4) {
        int kr = c * 16 + lr; if (kr > 299) kr = 299;
        glds16(Kb + (size_t)kr * 512 + k0n + sk, &sm.s1.k[cur ^ 1][c * 512 + lane * 8]);
      }
    }
    int k0 = t * 32;
    SB8 qF[2], kF[5];
#pragma unroll
    for (int m = 0; m < 2; ++m) {
      int r = m * 16 + fr;
      int ko = (k0 + kg) ^ ((r & 7) * 8);        // swizzled Q read
      qF[m].s = *(const s16x8*)&sm.s1.q[r * 512 + ko];
    }
#pragma unroll
    for (int n = 0; n < 5; ++n) {
      int kslot = (g ^ (fr & 3)) * 8;            // swizzled K read
      kF[n].s = *(const s16x8*)&sm.s1.k[cur][((ntBase + n) * 16 + fr) * 32 + kslot];
    }
#pragma unroll
    for (int m = 0; m < 2; ++m)
#pragma unroll
      for (int n = 0; n < 5; ++n)
        acc[m][n] = __builtin_amdgcn_mfma_f32_16x16x32_bf16(qF[m].b, kF[n].b, acc[m][n], 0, 0, 0);
    __syncthreads();
  }

  // spill scores to LDS (scaled); cols 300-319 garbage (never read)
  const float scale = 0.05773502691896258f;      // 1/sqrt(300)
#pragma unroll
  for (int m = 0; m < 2; ++m)
#pragma unroll
    for (int n = 0; n < 5; ++n) {
      int col = (ntBase + n) * 16 + fr;
      int rb = m * 16 + (lane >> 4) * 4;
#pragma unroll
      for (int jj = 0; jj < 4; ++jj)
        sm.S[(rb + jj) * 321 + col] = acc[m][n][jj] * scale;
    }
  __syncthreads();

  // softmax: 8 threads/row, 40 cols each (jj=7 scans only 280..299),
  // 4-way unrolled to break dependent LDS chains.
  {
    int r = tid >> 3, jj = tid & 7;
    int c0 = jj * 40;
    int cend = c0 + 40; if (cend > 300) cend = 300;
    const float* Sr = &sm.S[r * 321];
    float m0 = -1e30f, m1 = -1e30f, m2 = -1e30f, m3 = -1e30f;
    for (int c = c0; c < cend; c += 4) {         // (cend-c0) is 40 or 20
      m0 = fmaxf(m0, Sr[c]);     m1 = fmaxf(m1, Sr[c + 1]);
      m2 = fmaxf(m2, Sr[c + 2]); m3 = fmaxf(m3, Sr[c + 3]);
    }
    float mx = fmaxf(fmaxf(m0, m1), fmaxf(m2, m3));
    mx = fmaxf(mx, __shfl_xor(mx, 1));
    mx = fmaxf(mx, __shfl_xor(mx, 2));
    mx = fmaxf(mx, __shfl_xor(mx, 4));
    float s0 = 0.f, s1 = 0.f, s2 = 0.f, s3 = 0.f;
    float* Sw = &sm.S[r * 321];
    for (int c = c0; c < cend; c += 4) {
      float e0 = __expf(Sw[c] - mx);     Sw[c] = e0;     s0 += e0;
      float e1 = __expf(Sw[c + 1] - mx); Sw[c + 1] = e1; s1 += e1;
      float e2 = __expf(Sw[c + 2] - mx); Sw[c + 2] = e2; s2 += e2;
      float e3 = __expf(Sw[c + 3] - mx); Sw[c + 3] = e3; s3 += e3;
    }
    float sum = (s0 + s1) + (s2 + s3);
    sum += __shfl_xor(sum, 1);
    sum += __shfl_xor(sum, 2);
    sum += __shfl_xor(sum, 4);
    if (jj == 0) invS[r] = 1.0f / sum;
  }
  __syncthreads();

  // P write, same (r,jj) decomposition: 5 x 16B stores per thread.
  {
    int r = tid >> 3, jj = tid & 7;
    int qrow = qBase + r;
    if (qrow < 300) {
      float inv = invS[r];
      int c0 = jj * 40;
      const float* Sr = &sm.S[r * 321];
#pragma unroll
      for (int i = 0; i < 5; ++i) {
        union { unsigned short u[8]; s16x8 v; } o;
#pragma unroll
        for (int j2 = 0; j2 < 8; ++j2) {
          int c = c0 + i * 8 + j2;
          o.u[j2] = (c < 300) ? f2bf(Sr[c] * inv) : (unsigned short)0;
        }
        *(s16x8*)(Pb + (size_t)qrow * SP + c0 + i * 8) = o.v;
      }
    }
  }
}

// ---- K1b: V [B][300][512] -> Vt [B][512][320] bf16, zero-padded -----------
__global__ __launch_bounds__(256) void k_vt(const unsigned short* __restrict__ V,
                                            unsigned short* __restrict__ Vt) {
  __shared__ unsigned short tile[32][33];
  int kt = blockIdx.x, nt = blockIdx.y, b = blockIdx.z;
  const unsigned short* Vb = V + (size_t)b * S_ * 512;
  unsigned short* Vtb = Vt + (size_t)b * 512 * SP;
  int tc = threadIdx.x & 31, tr = threadIdx.x >> 5;   // tr 0..7
#pragma unroll
  for (int i = 0; i < 4; ++i) {
    int k = kt * 32 + tr + i * 8;
    int n = nt * 32 + tc;
    tile[tr + i * 8][tc] = (k < 300) ? Vb[(size_t)k * 512 + n] : (unsigned short)0;
  }
  __syncthreads();
#pragma unroll
  for (int i = 0; i < 4; ++i) {
    int n = nt * 32 + tr + i * 8;
    int k = kt * 32 + tc;
    Vtb[(size_t)n * SP + k] = tile[tc][tr + i * 8];
  }
}

// ---- K3: O = P @ V  (A = P [300][320], B^T = Vt [512][320], C fp32) -------
__global__ __launch_bounds__(256) void k_pv(const unsigned short* __restrict__ P,
                                            const unsigned short* __restrict__ Vt,
                                            float* __restrict__ O) {
  __shared__ short As[128 * 32];
  __shared__ short Bs[128 * 32];
  int bid = blockIdx.x;                       // 3072 = 8*384, 384 = 32*12
  int xc = bid & 7, j = bid >> 3;
  int b = xc + 8 * (j / 12);
  int tile = j % 12;
  int mt = tile >> 2, n0 = (tile & 3) * 128;
  int rowBase = mt * 128;
  const unsigned short* Pb  = P  + (size_t)b * S_ * SP;
  const unsigned short* Vtb = Vt + (size_t)b * 512 * SP;
  float* Ob = O + (size_t)b * S_ * 512;
  int tid = threadIdx.x, lane = tid & 63, wid = tid >> 6;
  int wr = wid >> 1, wc = wid & 1;
  int lr = lane >> 2, lk = (lane & 3) * 8;
  int kg = (lane >> 4) * 8, fr = lane & 15;
  f32x4 acc[4][4] = {};

  for (int t = 0; t < 10; ++t) {
    int k0 = t * 32;
    for (int c = wid * 2; c < wid * 2 + 2; ++c) {
      int row = rowBase + c * 16 + lr; if (row > 299) row = 299;
      glds16(Pb + (size_t)row * SP + k0 + lk, &As[c * 512 + lane * 8]);
    }
    for (int c = wid * 2; c < wid * 2 + 2; ++c)
      glds16(Vtb + (size_t)(n0 + c * 16 + lr) * SP + k0 + lk,
             &Bs[c * 512 + lane * 8]);
    __syncthreads();
    SB8 aF[4], bF[4];
#pragma unroll
    for (int m = 0; m < 4; ++m)
      aF[m].s = *(const s16x8*)&As[(wr * 64 + m * 16 + fr) * 32 + kg];
#pragma unroll
    for (int n = 0; n < 4; ++n)
      bF[n].s = *(const s16x8*)&Bs[(wc * 64 + n * 16 + fr) * 32 + kg];
#pragma unroll
    for (int m = 0; m < 4; ++m)
#pragma unroll
      for (int n = 0; n < 4; ++n)
        acc[m][n] = __builtin_amdgcn_mfma_f32_16x16x32_bf16(aF[m].b, bF[n].b, acc[m][n], 0, 0, 0);
    __syncthreads();
  }
  int fq = lane >> 4;
#pragma unroll
  for (int m = 0; m < 4; ++m)
#pragma unroll
    for (int n = 0; n < 4; ++n) {
      int col = n0 + wc * 64 + n * 16 + fr;
#pragma unroll
      for (int jj = 0; jj < 4; ++jj) {
        int row = rowBase + wr * 64 + m * 16 + fq * 4 + jj;
        if (row < 300) Ob[(size_t)row * 512 + col] = acc[m][n][jj];
      }
    }
}

// ---- launcher -------------------------------------------------------------
extern "C" void kernel_launch(void* const* d_in, const int* in_sizes, int n_in,
                              void* d_out, int out_size, void* d_ws, size_t ws_size,
                              hipStream_t stream) {
  const float* x = (const float*)d_in[0];
  const float* w = (const float*)d_in[1];
  float* out = (float*)d_out;
  char* ws = (char*)d_ws;
  // layout (bytes):
  //   Q  @ 0           (78,643,200)
  //   K  @ 78,643,200  (78,643,200)
  //   V  @ 157,286,400 (78,643,200)
  //   xb @ 235,929,600 (78,643,200)   -- dead after k_proj
  //   P  @ 235,929,600 (49,152,000)   -- aliases xb, written by k_attn_p
  //   Vt @ 0           (83,886,080)   -- aliases Q + K-head, written after k_attn_p
  //   Wt @ 314,572,800 (1,572,864)    -- total 316,145,664 B
  unsigned short* Q  = (unsigned short*)(ws);
  unsigned short* xb = (unsigned short*)(ws + 235929600LL);
  unsigned short* Pp = (unsigned short*)(ws + 235929600LL);
  unsigned short* Vt = (unsigned short*)(ws);
  unsigned short* Wt = (unsigned short*)(ws + 314572800LL);
  unsigned short* Kk = (unsigned short*)(ws + 78643200LL);
  unsigned short* Vv = (unsigned short*)(ws + 157286400LL);

  k_cvt_x<<<2048, 256, 0, stream>>>(x, xb, 4915200);
  k_wt<<<3072, 256, 0, stream>>>(w, Wt);
  k_proj<<<7200, 256, 0, stream>>>(xb, Wt, Q);          // writes Q,K,V (contiguous)
  k_attn_p<<<2560, 256, 0, stream>>>(Q, Kk, Pp);
  k_vt<<<dim3(10, 16, 256), 256, 0, stream>>>(Vv, Vt);  // Vt overwrites Q/K (dead)
  k_pv<<<3072, 256, 0, stream>>>(Pp, Vt, out);
}